// Round 8
// baseline (636.230 us; speedup 1.0000x reference)
//
#include <hip/hip_runtime.h>

#define BN_EPS 1e-5f

typedef unsigned short u16;
typedef __attribute__((ext_vector_type(8))) short bf16x8;
typedef __attribute__((ext_vector_type(4))) float f32x4;

__device__ __forceinline__ u16 f2bf(float x) {
  union { float f; unsigned int u; } v; v.f = x;
  unsigned int r = v.u + 0x7fffu + ((v.u >> 16) & 1u);
  return (u16)(r >> 16);
}
__device__ __forceinline__ float bf2f(u16 h) {
  union { unsigned int u; float f; } v; v.u = ((unsigned int)h) << 16;
  return v.f;
}

__device__ __forceinline__ float wave_reduce_sum(float v) {
#pragma unroll
  for (int off = 1; off < 64; off <<= 1) v += __shfl_xor(v, off, 64);
  return v;
}

// async global->LDS, 16B per lane. LDS dest = wave-uniform base + lane*16.
__device__ __forceinline__ void gload_lds16(const void* g, void* l) {
  __builtin_amdgcn_global_load_lds(
      (const __attribute__((address_space(1))) void*)g,
      (__attribute__((address_space(3))) void*)l, 16, 0, 0);
}

// ---------------------------------------------------------------------------
// Kernel 1: embeddings -> fm_first (N x 576 bf16) + partial[n] (fp32), and
// (blocks >= NBE) W1 -> W1h bf16 padded to 512 rows (rows>=400 zero).
// PROBE: reps-amplified (idempotent recompute; no LDS -> no cross-rep hazard).
// ---------------------------------------------------------------------------
#define NBE 4096  // N/4 embed blocks
__global__ __launch_bounds__(256) void embed_prep(
    const float* __restrict__ Xi_dense, const float* __restrict__ Xv,
    const float* __restrict__ Wd, const float* __restrict__ bd,
    const float* __restrict__ tables, const int* __restrict__ Xi_cat,
    const float* __restrict__ bias_vec, const float* __restrict__ W1,
    u16* __restrict__ fm_first, float* __restrict__ partial,
    u16* __restrict__ W1h, int reps) {
  const int t = threadIdx.x;
  for (int rep = 0; rep < reps; ++rep) {
    if (blockIdx.x >= NBE) {  // W1 conversion: 512*576 = 72 blocks * 4096
      const int base = (blockIdx.x - NBE) * 4096;
#pragma unroll
      for (int e = 0; e < 16; ++e) {
        const int idx = base + e * 256 + t;
        const int r = idx / 576;
        const int j = idx - r * 576;
        W1h[idx] = (r < 400) ? f2bf(W1[r * 576 + j]) : (u16)0;
      }
      continue;
    }
    const int lane = t & 63;
    const int n = blockIdx.x * 4 + (t >> 6);

    const float* xv = Xv + n * 36;
    float sum_all = 0.f, s_e = 0.f, q_e = 0.f;

#pragma unroll
    for (int k = 0; k < 9; ++k) {
      const int idx = lane + 64 * k;
      const int f = idx >> 4;
      const int e = idx & 15;
      float val;
      if (f < 26) {
        val = Xi_dense[n * 26 + f] * Wd[f * 16 + e] + bd[f * 16 + e];
      } else {
        const int fc = f - 26;
        const int row = Xi_cat[n * 10 + fc];
        val = tables[(size_t)fc * 200000 * 16 + (size_t)row * 16 + e];
      }
      val *= xv[f];
      fm_first[(size_t)n * 576 + idx] = f2bf(val);
      sum_all += val;
      s_e += val;
      q_e += val * val;
    }

    float s_tot = s_e;
    s_tot += __shfl_xor(s_tot, 16, 64);
    s_tot += __shfl_xor(s_tot, 32, 64);
    float q_tot = q_e;
    q_tot += __shfl_xor(q_tot, 16, 64);
    q_tot += __shfl_xor(q_tot, 32, 64);

    const float fm2 = 0.5f * (s_tot * s_tot - q_tot);
    const float red1 = wave_reduce_sum(sum_all);
    const float red2 = wave_reduce_sum(fm2) * 0.25f;
    if (lane == 0) partial[n] = red1 + red2 + bias_vec[n];
  }
}

// ---------------------------------------------------------------------------
// bf16 MFMA GEMM body (r5-best config). BM=64 BN=128 BK=32, 256 thr =
// 4 waves (2 row x 2 col), 2xNFR 16x16x32 frags/wave. NFR=2: tail tile.
// ---------------------------------------------------------------------------
template <int NFR>
__device__ __forceinline__ void gemm_body(
    const u16* __restrict__ A, int lda, const u16* __restrict__ W, int ldw,
    const float* __restrict__ bias, int nbias, u16* __restrict__ Y, int ldc,
    int Ncap, float* __restrict__ pS, float* __restrict__ pQ, int K, int nxb,
    int bx, int by, u16* As, u16* Bs, float (&rS)[2][4][2][16],
    float (&rQ)[2][4][2][16]) {
  const int t = threadIdx.x;
  const int bm = bx * 64;
  const int bn = by * 128;
  const int wid = t >> 6, lane = t & 63;
  const int wr = wid >> 1, wc = wid & 1;
  const int lr = lane & 15, lk = (lane >> 4) * 8;
  const int sr = lane >> 2;       // staging row within 16-row chunk
  const int sk = (lane & 3) * 8;  // staging k offset (elements)
  const bool active = (NFR == 4) || (wc == 0);

  f32x4 acc[2][NFR] = {};

  for (int kt = 0; kt < K; kt += 32) {
    // A: 4 chunks of 16 rows; wave w stages chunk w.
    gload_lds16(&A[(size_t)(bm + wid * 16 + sr) * lda + kt + sk],
                &As[wid * 512]);
    // B: 8 chunks; wave w stages chunks 2w, 2w+1 (tail: only c<2).
#pragma unroll
    for (int i = 0; i < 2; ++i) {
      const int c = wid * 2 + i;
      if (NFR == 4 || c < 2)
        gload_lds16(&W[(size_t)(bn + c * 16 + sr) * ldw + kt + sk],
                    &Bs[c * 512]);
    }
    __syncthreads();

    if (active) {
      bf16x8 af[2], bfv[NFR];
#pragma unroll
      for (int mf = 0; mf < 2; ++mf)
        af[mf] = *(const bf16x8*)&As[(wr * 32 + mf * 16 + lr) * 32 + lk];
#pragma unroll
      for (int nf = 0; nf < NFR; ++nf)
        bfv[nf] = *(const bf16x8*)&Bs[(wc * 64 + nf * 16 + lr) * 32 + lk];
#pragma unroll
      for (int mf = 0; mf < 2; ++mf)
#pragma unroll
        for (int nf = 0; nf < NFR; ++nf)
          acc[mf][nf] = __builtin_amdgcn_mfma_f32_16x16x32_bf16(
              af[mf], bfv[nf], acc[mf][nf], 0, 0, 0);
    }
    __syncthreads();
  }

  // epilogue: bias, bf16 store, per-block column stats
  const int l4 = (lane >> 4) * 4;
  if (active) {
#pragma unroll
    for (int nf = 0; nf < NFR; ++nf) {
      const int col = bn + wc * 64 + nf * 16 + lr;
      const float bb = (col < nbias) ? bias[col] : 0.f;
      float s = 0.f, q = 0.f;
#pragma unroll
      for (int mf = 0; mf < 2; ++mf) {
#pragma unroll
        for (int r = 0; r < 4; ++r) {
          const int row = bm + wr * 32 + mf * 16 + l4 + r;
          const float v = acc[mf][nf][r] + bb;
          s += v;
          q += v * v;
          if (col < Ncap) Y[(size_t)row * ldc + col] = f2bf(v);
        }
      }
      s += __shfl_xor(s, 16, 64);
      s += __shfl_xor(s, 32, 64);
      q += __shfl_xor(q, 16, 64);
      q += __shfl_xor(q, 32, 64);
      if (lane < 16) {
        rS[wc][nf][wr][lr] = s;
        rQ[wc][nf][wr][lr] = q;
      }
    }
  }
  __syncthreads();
  if (t < (NFR == 4 ? 128 : 32)) {  // t == wc*64 + nf*16 + c
    const int wcc = t >> 6, nff = (t >> 4) & 3, c = t & 15;
    pS[(size_t)(bn + t) * nxb + bx] =
        rS[wcc][nff][0][c] + rS[wcc][nff][1][c];
    pQ[(size_t)(bn + t) * nxb + bx] =
        rQ[wcc][nff][0][c] + rQ[wcc][nff][1][c];
  }
}

// 1-D grid, y-inner ordering + XCD-chunked swizzle. PROBE: reps-amplified
// (idempotent; reps separated by barriers -> no hazard).
__global__ __launch_bounds__(256) void gemm_bf16(
    const u16* __restrict__ A, int lda,
    const u16* __restrict__ W, int ldw,
    const float* __restrict__ bias, int nbias,
    u16* __restrict__ Y, int ldc, int Ncap,
    float* __restrict__ pS, float* __restrict__ pQ, int K, int nxb,
    int reps) {
  __shared__ u16 As[64 * 32];
  __shared__ u16 Bs[128 * 32];
  __shared__ float rS[2][4][2][16];
  __shared__ float rQ[2][4][2][16];
  const int bid = blockIdx.x;
  const int l = (bid & 7) * (gridDim.x >> 3) + (bid >> 3);
  const int bx = l >> 2, by = l & 3;
  for (int rep = 0; rep < reps; ++rep) {
    if (by < 3)
      gemm_body<4>(A, lda, W, ldw, bias, nbias, Y, ldc, Ncap, pS, pQ, K, nxb,
                   bx, by, As, Bs, rS, rQ);
    else
      gemm_body<2>(A, lda, W, ldw, bias, nbias, Y, ldc, Ncap, pS, pQ, K, nxb,
                   bx, by, As, Bs, rS, rQ);
    __syncthreads();
  }
}

// ---------------------------------------------------------------------------
// bn_ac: wave-per-column BN finalize. 100 blocks x 4 waves = 400 cols.
// ---------------------------------------------------------------------------
__global__ __launch_bounds__(256) void bn_ac(
    const float* __restrict__ pS, const float* __restrict__ pQ,
    const float* __restrict__ g, const float* __restrict__ be,
    float* __restrict__ a, float* __restrict__ c, int nxb) {
  const int wid = threadIdx.x >> 6, lane = threadIdx.x & 63;
  const int col = blockIdx.x * 4 + wid;  // grid=100 -> col<400
  float S = 0.f, Q = 0.f;
  for (int i = lane; i < nxb; i += 64) {
    S += pS[(size_t)col * nxb + i];
    Q += pQ[(size_t)col * nxb + i];
  }
#pragma unroll
  for (int off = 1; off < 64; off <<= 1) {
    S += __shfl_xor(S, off, 64);
    Q += __shfl_xor(Q, off, 64);
  }
  if (lane == 0) {
    const float mu = S * (1.f / 16384.f);
    const float var = Q * (1.f / 16384.f) - mu * mu;
    const float aa = g[col] * rsqrtf(var + BN_EPS);
    a[col] = aa;
    c[col] = be[col] - mu * aa;
  }
}

// ---------------------------------------------------------------------------
// prep2: fold BN1 affine into W2/b2 (a1/c1 from global, vectorized float4).
// ---------------------------------------------------------------------------
__global__ __launch_bounds__(256) void prep2(
    const float* __restrict__ a1, const float* __restrict__ c1,
    const float* __restrict__ W2, const float* __restrict__ b2,
    u16* __restrict__ W2p, float* __restrict__ b2p) {
  const int t = threadIdx.x;
  const int lane = t & 63;
  const int row = blockIdx.x * 4 + (t >> 6);
  const ushort4 z4 = {0, 0, 0, 0};
  if (row >= 400) {
    const int j1 = lane * 4;
    *(ushort4*)&W2p[(size_t)row * 416 + j1] = z4;
    const int j2 = 256 + lane * 4;
    if (j2 < 416) *(ushort4*)&W2p[(size_t)row * 416 + j2] = z4;
    if (lane == 0) b2p[row] = 0.f;
    return;
  }
  float dot = 0.f;
  {  // phase 1: j = lane*4 in [0,256)
    const int j = lane * 4;
    const float4 w = *(const float4*)&W2[(size_t)row * 400 + j];
    const float4 la = *(const float4*)&a1[j];
    const float4 lc = *(const float4*)&c1[j];
    ushort4 o = {f2bf(w.x * la.x), f2bf(w.y * la.y), f2bf(w.z * la.z),
                 f2bf(w.w * la.w)};
    *(ushort4*)&W2p[(size_t)row * 416 + j] = o;
    dot += w.x * lc.x + w.y * lc.y + w.z * lc.z + w.w * lc.w;
  }
  {  // phase 2: j = 256 + lane*4 in [256,512)
    const int j = 256 + lane * 4;
    if (j < 400) {
      const float4 w = *(const float4*)&W2[(size_t)row * 400 + j];
      const float4 la = *(const float4*)&a1[j];
      const float4 lc = *(const float4*)&c1[j];
      ushort4 o = {f2bf(w.x * la.x), f2bf(w.y * la.y), f2bf(w.z * la.z),
                   f2bf(w.w * la.w)};
      *(ushort4*)&W2p[(size_t)row * 416 + j] = o;
      dot += w.x * lc.x + w.y * lc.y + w.z * lc.z + w.w * lc.w;
    } else if (j < 416) {
      *(ushort4*)&W2p[(size_t)row * 416 + j] = z4;
    }
  }
  dot = wave_reduce_sum(dot);
  if (lane == 0) b2p[row] = b2[row] + dot;
}

// ---------------------------------------------------------------------------
// final: out[n] = partial[n] + sum_j (a2[j]*Y2[n,j] + c2[j])
// PROBE: reps-amplified (register/global only, no LDS).
// ---------------------------------------------------------------------------
__global__ __launch_bounds__(256) void final_kernel(
    const u16* __restrict__ Y2, const float* __restrict__ a2,
    const float* __restrict__ c2, const float* __restrict__ partial,
    float* __restrict__ out, int reps) {
  const int t = threadIdx.x;
  const int lane = t & 63;
  const int wid = t >> 6;
  const int j0 = lane * 8;
  for (int rep = 0; rep < reps; ++rep) {
    float ar[8], cr[8];
    if (j0 < 400) {
      const float4 a0 = *(const float4*)&a2[j0];
      const float4 a1v = *(const float4*)&a2[j0 + 4];
      const float4 c0 = *(const float4*)&c2[j0];
      const float4 c1v = *(const float4*)&c2[j0 + 4];
      ar[0] = a0.x; ar[1] = a0.y; ar[2] = a0.z; ar[3] = a0.w;
      ar[4] = a1v.x; ar[5] = a1v.y; ar[6] = a1v.z; ar[7] = a1v.w;
      cr[0] = c0.x; cr[1] = c0.y; cr[2] = c0.z; cr[3] = c0.w;
      cr[4] = c1v.x; cr[5] = c1v.y; cr[6] = c1v.z; cr[7] = c1v.w;
    } else {
#pragma unroll
      for (int k = 0; k < 8; ++k) { ar[k] = 0.f; cr[k] = 0.f; }
    }
#pragma unroll
    for (int r = 0; r < 4; ++r) {
      const int n = blockIdx.x * 16 + wid * 4 + r;
      float acc = 0.f;
      if (j0 < 400) {
        const bf16x8 y = *(const bf16x8*)&Y2[(size_t)n * 400 + j0];
#pragma unroll
        for (int k = 0; k < 8; ++k)
          acc += fmaf(ar[k], bf2f((u16)y[k]), cr[k]);
      }
      acc = wave_reduce_sum(acc);
      if (lane == 0) out[n] = partial[n] + acc;
    }
  }
}

extern "C" void kernel_launch(void* const* d_in, const int* in_sizes, int n_in,
                              void* d_out, int out_size, void* d_ws,
                              size_t ws_size, hipStream_t stream) {
  const float* Xi_dense = (const float*)d_in[0];
  const float* Xv = (const float*)d_in[1];
  const float* Wd = (const float*)d_in[2];
  const float* bd = (const float*)d_in[3];
  const float* tables = (const float*)d_in[4];
  const float* W1 = (const float*)d_in[5];
  const float* b1 = (const float*)d_in[6];
  const float* g1 = (const float*)d_in[7];
  const float* be1 = (const float*)d_in[8];
  const float* W2 = (const float*)d_in[9];
  const float* b2 = (const float*)d_in[10];
  const float* g2 = (const float*)d_in[11];
  const float* be2 = (const float*)d_in[12];
  const float* bias_vec = (const float*)d_in[13];
  const int* Xi_cat = (const int*)d_in[14];

  constexpr int N = 16384;
  constexpr int DIN = 576;
  constexpr int H = 400;
  constexpr int KP = 416;   // H padded to K-mult-of-32 for gemm2
  constexpr int WPAD = 512; // weight rows padded for unpredicated staging
  constexpr int NXB = 256;  // gemm x-blocks (N/64)

  u16* fm_first = (u16*)d_ws;                        // N*576
  u16* Y1h = fm_first + (size_t)N * DIN;             // N*416
  u16* Y2h = Y1h + (size_t)N * KP;                   // N*400
  u16* W1h = Y2h + (size_t)N * H;                    // 512*576
  u16* W2p = W1h + (size_t)WPAD * DIN;               // 512*416
  float* fptr = (float*)(W2p + (size_t)WPAD * KP);
  float* partial = fptr;                             // N
  float* pS = partial + N;                           // 512*256
  float* pQ = pS + WPAD * NXB;                       // 512*256
  float* a1 = pQ + WPAD * NXB;                       // 512
  float* c1 = a1 + WPAD;
  float* a2 = c1 + WPAD;
  float* c2 = a2 + WPAD;
  float* b2p = c2 + WPAD;                            // 512

  // PROBE ROUND: reps-amplified dispatches so per-kernel counters surface
  // above the harness's 73us poison-fills in the top-5 display.
  embed_prep<<<NBE + 72, 256, 0, stream>>>(Xi_dense, Xv, Wd, bd, tables,
                                           Xi_cat, bias_vec, W1, fm_first,
                                           partial, W1h, 16);

  gemm_bf16<<<NXB * 4, 256, 0, stream>>>(fm_first, DIN, W1h, DIN, b1, H,
                                         Y1h, KP, KP, pS, pQ, DIN, NXB, 8);

  bn_ac<<<100, 256, 0, stream>>>(pS, pQ, g1, be1, a1, c1, NXB);
  prep2<<<128, 256, 0, stream>>>(a1, c1, W2, b2, W2p, b2p);

  gemm_bf16<<<NXB * 4, 256, 0, stream>>>(Y1h, KP, W2p, KP, b2p, H,
                                         Y2h, H, H, pS, pQ, KP, NXB, 12);

  bn_ac<<<100, 256, 0, stream>>>(pS, pQ, g2, be2, a2, c2, NXB);

  final_kernel<<<N / 16, 256, 0, stream>>>(Y2h, a2, c2, partial,
                                           (float*)d_out, 16);
}

// Round 9
// 69.793 us; speedup vs baseline: 9.1160x; 9.1160x over previous
//
#include <hip/hip_runtime.h>

#define BN_EPS 1e-5f

typedef unsigned short u16;
typedef __attribute__((ext_vector_type(8))) short bf16x8;
typedef __attribute__((ext_vector_type(4))) float f32x4;

__device__ __forceinline__ u16 f2bf(float x) {
  union { float f; unsigned int u; } v; v.f = x;
  unsigned int r = v.u + 0x7fffu + ((v.u >> 16) & 1u);
  return (u16)(r >> 16);
}
__device__ __forceinline__ float bf2f(u16 h) {
  union { unsigned int u; float f; } v; v.u = ((unsigned int)h) << 16;
  return v.f;
}

__device__ __forceinline__ float wave_reduce_sum(float v) {
#pragma unroll
  for (int off = 1; off < 64; off <<= 1) v += __shfl_xor(v, off, 64);
  return v;
}

// async global->LDS, 16B per lane. LDS dest = wave-uniform base + lane*16.
__device__ __forceinline__ void gload_lds16(const void* g, void* l) {
  __builtin_amdgcn_global_load_lds(
      (const __attribute__((address_space(1))) void*)g,
      (__attribute__((address_space(3))) void*)l, 16, 0, 0);
}

// ---------------------------------------------------------------------------
// embed_prep: blocks [0,256): 64 rows each -> fm_first (bf16) + partial[n].
//   LDS-staged inputs (coalesced, conflict-free strides); thread (r=t>>2,
//   q=t&3) computes 18 bf16x8 chunks: fields f = (q>>1)+2k, e-half (q&1)*8.
//   4 q-lanes of a row write contiguous 64B. FM reductions: 4-lane shuffles.
// blocks [256,328): W1 -> W1h bf16 padded to 512 rows; block 256 also zeroes
//   the 4x512 atomic stat accumulators (aS1,aQ1,aS2,aQ2 contiguous).
// ---------------------------------------------------------------------------
__global__ __launch_bounds__(256) void embed_prep(
    const float* __restrict__ Xi_dense, const float* __restrict__ Xv,
    const float* __restrict__ Wd, const float* __restrict__ bd,
    const float* __restrict__ tables, const int* __restrict__ Xi_cat,
    const float* __restrict__ bias_vec, const float* __restrict__ W1,
    u16* __restrict__ fm_first, float* __restrict__ partial,
    u16* __restrict__ W1h, float* __restrict__ statz) {
  const int t = threadIdx.x;
  if (blockIdx.x >= 256) {  // W1 conversion region (+ stat zeroing)
    const int bb = blockIdx.x - 256;
    if (bb == 0) {
#pragma unroll
      for (int i = 0; i < 8; ++i) statz[i * 256 + t] = 0.f;  // 2048 floats
    }
    const int base = bb * 4096;
#pragma unroll
    for (int e = 0; e < 16; ++e) {
      const int idx = base + e * 256 + t;
      const int r = idx / 576;
      const int j = idx - r * 576;
      W1h[idx] = (r < 400) ? f2bf(W1[r * 576 + j]) : (u16)0;
    }
    return;
  }

  __shared__ float Xvs[64 * 37];
  __shared__ float Xds[64 * 27];
  __shared__ int Cis[64 * 11];
  __shared__ float Wds[416], Bds[416];
  const int n0 = blockIdx.x * 64;

  for (int i = t; i < 2304; i += 256) {
    const int r = i / 36;
    Xvs[r * 37 + (i - r * 36)] = Xv[n0 * 36 + i];
  }
  for (int i = t; i < 1664; i += 256) {
    const int r = i / 26;
    Xds[r * 27 + (i - r * 26)] = Xi_dense[n0 * 26 + i];
  }
  for (int i = t; i < 640; i += 256) {
    const int r = i / 10;
    Cis[r * 11 + (i - r * 10)] = Xi_cat[n0 * 10 + i];
  }
  for (int i = t; i < 416; i += 256) {
    Wds[i] = Wd[i];
    Bds[i] = bd[i];
  }
  __syncthreads();

  const int r = t >> 2, q = t & 3;
  const int n = n0 + r;
  const int fpar = q >> 1, eh = (q & 1) * 8;
  float s8[8] = {}, q8[8] = {};
  float sum_all = 0.f;
  u16* frow = fm_first + (size_t)n * 576;

#pragma unroll
  for (int k = 0; k < 18; ++k) {
    const int f = fpar + 2 * k;
    const float xvv = Xvs[r * 37 + f];
    float val[8];
    if (k < 13) {  // dense fields (f<26 for both parities) — compile-time
      const float xd = Xds[r * 27 + f];
      const float4 w0 = *(const float4*)&Wds[f * 16 + eh];
      const float4 w1 = *(const float4*)&Wds[f * 16 + eh + 4];
      const float4 b0 = *(const float4*)&Bds[f * 16 + eh];
      const float4 b1 = *(const float4*)&Bds[f * 16 + eh + 4];
      val[0] = fmaf(xd, w0.x, b0.x) * xvv;
      val[1] = fmaf(xd, w0.y, b0.y) * xvv;
      val[2] = fmaf(xd, w0.z, b0.z) * xvv;
      val[3] = fmaf(xd, w0.w, b0.w) * xvv;
      val[4] = fmaf(xd, w1.x, b1.x) * xvv;
      val[5] = fmaf(xd, w1.y, b1.y) * xvv;
      val[6] = fmaf(xd, w1.z, b1.z) * xvv;
      val[7] = fmaf(xd, w1.w, b1.w) * xvv;
    } else {  // categorical gather
      const int fc = f - 26;
      const int row = Cis[r * 11 + fc];
      const float* tp =
          tables + ((size_t)fc * 200000 + (size_t)row) * 16 + eh;
      const float4 v0 = *(const float4*)tp;
      const float4 v1 = *(const float4*)(tp + 4);
      val[0] = v0.x * xvv;
      val[1] = v0.y * xvv;
      val[2] = v0.z * xvv;
      val[3] = v0.w * xvv;
      val[4] = v1.x * xvv;
      val[5] = v1.y * xvv;
      val[6] = v1.z * xvv;
      val[7] = v1.w * xvv;
    }
    bf16x8 o;
#pragma unroll
    for (int j = 0; j < 8; ++j) {
      s8[j] += val[j];
      q8[j] += val[j] * val[j];
      sum_all += val[j];
      o[j] = (short)f2bf(val[j]);
    }
    *(bf16x8*)&frow[f * 16 + eh] = o;
  }

  // combine field parities (lane ^2 has same row, same e-half, other parity)
  float fm2h = 0.f;
#pragma unroll
  for (int j = 0; j < 8; ++j) {
    const float se = s8[j] + __shfl_xor(s8[j], 2, 64);
    const float qe = q8[j] + __shfl_xor(q8[j], 2, 64);
    fm2h += se * se - qe;
  }
  const float fm2 = 0.5f * (fm2h + __shfl_xor(fm2h, 1, 64));  // both e-halves
  float srow = sum_all + __shfl_xor(sum_all, 1, 64);
  srow += __shfl_xor(srow, 2, 64);
  if (q == 0) partial[n] = srow + fm2 + bias_vec[n];
}

// ---------------------------------------------------------------------------
// bf16 MFMA GEMM body (r5-best config). BM=64 BN=128 BK=32, 256 thr =
// 4 waves (2 row x 2 col), 2xNFR 16x16x32 frags/wave. NFR=2: tail tile.
// Stats: per-block column S/Q atomically accumulated into aS/aQ[col].
// ---------------------------------------------------------------------------
template <int NFR>
__device__ __forceinline__ void gemm_body(
    const u16* __restrict__ A, int lda, const u16* __restrict__ W, int ldw,
    const float* __restrict__ bias, int nbias, u16* __restrict__ Y, int ldc,
    int Ncap, float* __restrict__ aS, float* __restrict__ aQ, int K,
    int bx, int by, u16* As, u16* Bs, float (&rS)[2][4][2][16],
    float (&rQ)[2][4][2][16]) {
  const int t = threadIdx.x;
  const int bm = bx * 64;
  const int bn = by * 128;
  const int wid = t >> 6, lane = t & 63;
  const int wr = wid >> 1, wc = wid & 1;
  const int lr = lane & 15, lk = (lane >> 4) * 8;
  const int sr = lane >> 2;       // staging row within 16-row chunk
  const int sk = (lane & 3) * 8;  // staging k offset (elements)
  const bool active = (NFR == 4) || (wc == 0);

  f32x4 acc[2][NFR] = {};

  for (int kt = 0; kt < K; kt += 32) {
    gload_lds16(&A[(size_t)(bm + wid * 16 + sr) * lda + kt + sk],
                &As[wid * 512]);
#pragma unroll
    for (int i = 0; i < 2; ++i) {
      const int c = wid * 2 + i;
      if (NFR == 4 || c < 2)
        gload_lds16(&W[(size_t)(bn + c * 16 + sr) * ldw + kt + sk],
                    &Bs[c * 512]);
    }
    __syncthreads();

    if (active) {
      bf16x8 af[2], bfv[NFR];
#pragma unroll
      for (int mf = 0; mf < 2; ++mf)
        af[mf] = *(const bf16x8*)&As[(wr * 32 + mf * 16 + lr) * 32 + lk];
#pragma unroll
      for (int nf = 0; nf < NFR; ++nf)
        bfv[nf] = *(const bf16x8*)&Bs[(wc * 64 + nf * 16 + lr) * 32 + lk];
#pragma unroll
      for (int mf = 0; mf < 2; ++mf)
#pragma unroll
        for (int nf = 0; nf < NFR; ++nf)
          acc[mf][nf] = __builtin_amdgcn_mfma_f32_16x16x32_bf16(
              af[mf], bfv[nf], acc[mf][nf], 0, 0, 0);
    }
    __syncthreads();
  }

  // epilogue: bias, bf16 store, per-block column stats
  const int l4 = (lane >> 4) * 4;
  if (active) {
#pragma unroll
    for (int nf = 0; nf < NFR; ++nf) {
      const int col = bn + wc * 64 + nf * 16 + lr;
      const float bb = (col < nbias) ? bias[col] : 0.f;
      float s = 0.f, q = 0.f;
#pragma unroll
      for (int mf = 0; mf < 2; ++mf) {
#pragma unroll
        for (int r = 0; r < 4; ++r) {
          const int row = bm + wr * 32 + mf * 16 + l4 + r;
          const float v = acc[mf][nf][r] + bb;
          s += v;
          q += v * v;
          if (col < Ncap) Y[(size_t)row * ldc + col] = f2bf(v);
        }
      }
      s += __shfl_xor(s, 16, 64);
      s += __shfl_xor(s, 32, 64);
      q += __shfl_xor(q, 16, 64);
      q += __shfl_xor(q, 32, 64);
      if (lane < 16) {
        rS[wc][nf][wr][lr] = s;
        rQ[wc][nf][wr][lr] = q;
      }
    }
  }
  __syncthreads();
  if (t < (NFR == 4 ? 128 : 32)) {  // t == wc*64 + nf*16 + c
    const int wcc = t >> 6, nff = (t >> 4) & 3, c = t & 15;
    atomicAdd(&aS[bn + t], rS[wcc][nff][0][c] + rS[wcc][nff][1][c]);
    atomicAdd(&aQ[bn + t], rQ[wcc][nff][0][c] + rQ[wcc][nff][1][c]);
  }
}

// 1-D grid, y-inner ordering + XCD-chunked swizzle (grid %8 == 0).
__global__ __launch_bounds__(256) void gemm_bf16(
    const u16* __restrict__ A, int lda,
    const u16* __restrict__ W, int ldw,
    const float* __restrict__ bias, int nbias,
    u16* __restrict__ Y, int ldc, int Ncap,
    float* __restrict__ aS, float* __restrict__ aQ, int K) {
  __shared__ u16 As[64 * 32];
  __shared__ u16 Bs[128 * 32];
  __shared__ float rS[2][4][2][16];
  __shared__ float rQ[2][4][2][16];
  const int bid = blockIdx.x;
  const int l = (bid & 7) * (gridDim.x >> 3) + (bid >> 3);
  const int bx = l >> 2, by = l & 3;
  if (by < 3)
    gemm_body<4>(A, lda, W, ldw, bias, nbias, Y, ldc, Ncap, aS, aQ, K,
                 bx, by, As, Bs, rS, rQ);
  else
    gemm_body<2>(A, lda, W, ldw, bias, nbias, Y, ldc, Ncap, aS, aQ, K,
                 bx, by, As, Bs, rS, rQ);
}

// ---------------------------------------------------------------------------
// prep2: BN1 affine computed INLINE per lane from atomic stats, folded into
// W2/b2: W2p[i][j] = bf16(W2[i][j]*a1[j]) (512x416, zeros beyond);
// b2p[i] = b2[i] + sum_j W2[i][j]*c1[j].  128 blocks x 4 rows.
// ---------------------------------------------------------------------------
__device__ __forceinline__ void bn_affine4(const float* aS, const float* aQ,
                                           const float* g, const float* be,
                                           int j, float4& aa, float4& cc) {
  const float4 S = *(const float4*)&aS[j];
  const float4 Q = *(const float4*)&aQ[j];
  const float4 G = *(const float4*)&g[j];
  const float4 E = *(const float4*)&be[j];
  const float inv = 1.f / 16384.f;
  float mu, var;
  mu = S.x * inv; var = Q.x * inv - mu * mu;
  aa.x = G.x * rsqrtf(var + BN_EPS); cc.x = E.x - mu * aa.x;
  mu = S.y * inv; var = Q.y * inv - mu * mu;
  aa.y = G.y * rsqrtf(var + BN_EPS); cc.y = E.y - mu * aa.y;
  mu = S.z * inv; var = Q.z * inv - mu * mu;
  aa.z = G.z * rsqrtf(var + BN_EPS); cc.z = E.z - mu * aa.z;
  mu = S.w * inv; var = Q.w * inv - mu * mu;
  aa.w = G.w * rsqrtf(var + BN_EPS); cc.w = E.w - mu * aa.w;
}

__global__ __launch_bounds__(256) void prep2(
    const float* __restrict__ aS1, const float* __restrict__ aQ1,
    const float* __restrict__ g1, const float* __restrict__ be1,
    const float* __restrict__ W2, const float* __restrict__ b2,
    u16* __restrict__ W2p, float* __restrict__ b2p) {
  const int t = threadIdx.x;
  const int lane = t & 63;
  const int row = blockIdx.x * 4 + (t >> 6);
  const ushort4 z4 = {0, 0, 0, 0};
  if (row >= 400) {
    const int j1 = lane * 4;
    *(ushort4*)&W2p[(size_t)row * 416 + j1] = z4;
    const int j2 = 256 + lane * 4;
    if (j2 < 416) *(ushort4*)&W2p[(size_t)row * 416 + j2] = z4;
    if (lane == 0) b2p[row] = 0.f;
    return;
  }
  float dot = 0.f;
  {  // phase 1: j = lane*4 in [0,256)
    const int j = lane * 4;
    float4 aa, cc;
    bn_affine4(aS1, aQ1, g1, be1, j, aa, cc);
    const float4 w = *(const float4*)&W2[(size_t)row * 400 + j];
    ushort4 o = {f2bf(w.x * aa.x), f2bf(w.y * aa.y), f2bf(w.z * aa.z),
                 f2bf(w.w * aa.w)};
    *(ushort4*)&W2p[(size_t)row * 416 + j] = o;
    dot += w.x * cc.x + w.y * cc.y + w.z * cc.z + w.w * cc.w;
  }
  {  // phase 2: j = 256 + lane*4 in [256,512)
    const int j = 256 + lane * 4;
    if (j < 400) {
      float4 aa, cc;
      bn_affine4(aS1, aQ1, g1, be1, j, aa, cc);
      const float4 w = *(const float4*)&W2[(size_t)row * 400 + j];
      ushort4 o = {f2bf(w.x * aa.x), f2bf(w.y * aa.y), f2bf(w.z * aa.z),
                   f2bf(w.w * aa.w)};
      *(ushort4*)&W2p[(size_t)row * 416 + j] = o;
      dot += w.x * cc.x + w.y * cc.y + w.z * cc.z + w.w * cc.w;
    } else if (j < 416) {
      *(ushort4*)&W2p[(size_t)row * 416 + j] = z4;
    }
  }
  dot = wave_reduce_sum(dot);
  if (lane == 0) b2p[row] = b2[row] + dot;
}

// ---------------------------------------------------------------------------
// final: BN2 affine inline per lane (8 cols) + out[n] = partial[n] +
// sum_j (a2[j]*Y2[n,j] + c2[j]).  1024 blocks x 4 waves x 4 rows.
// ---------------------------------------------------------------------------
__global__ __launch_bounds__(256) void final_kernel(
    const u16* __restrict__ Y2, const float* __restrict__ aS2,
    const float* __restrict__ aQ2, const float* __restrict__ g2,
    const float* __restrict__ be2, const float* __restrict__ partial,
    float* __restrict__ out) {
  const int t = threadIdx.x;
  const int lane = t & 63;
  const int wid = t >> 6;
  const int j0 = lane * 8;
  float ar[8], cr[8];
  if (j0 < 400) {
    float4 aa0, cc0, aa1, cc1;
    bn_affine4(aS2, aQ2, g2, be2, j0, aa0, cc0);
    bn_affine4(aS2, aQ2, g2, be2, j0 + 4, aa1, cc1);
    ar[0] = aa0.x; ar[1] = aa0.y; ar[2] = aa0.z; ar[3] = aa0.w;
    ar[4] = aa1.x; ar[5] = aa1.y; ar[6] = aa1.z; ar[7] = aa1.w;
    cr[0] = cc0.x; cr[1] = cc0.y; cr[2] = cc0.z; cr[3] = cc0.w;
    cr[4] = cc1.x; cr[5] = cc1.y; cr[6] = cc1.z; cr[7] = cc1.w;
  } else {
#pragma unroll
    for (int k = 0; k < 8; ++k) { ar[k] = 0.f; cr[k] = 0.f; }
  }
#pragma unroll
  for (int r = 0; r < 4; ++r) {
    const int n = blockIdx.x * 16 + wid * 4 + r;
    float acc = 0.f;
    if (j0 < 400) {
      const bf16x8 y = *(const bf16x8*)&Y2[(size_t)n * 400 + j0];
#pragma unroll
      for (int k = 0; k < 8; ++k)
        acc += fmaf(ar[k], bf2f((u16)y[k]), cr[k]);
    }
    acc = wave_reduce_sum(acc);
    if (lane == 0) out[n] = partial[n] + acc;
  }
}

extern "C" void kernel_launch(void* const* d_in, const int* in_sizes, int n_in,
                              void* d_out, int out_size, void* d_ws,
                              size_t ws_size, hipStream_t stream) {
  const float* Xi_dense = (const float*)d_in[0];
  const float* Xv = (const float*)d_in[1];
  const float* Wd = (const float*)d_in[2];
  const float* bd = (const float*)d_in[3];
  const float* tables = (const float*)d_in[4];
  const float* W1 = (const float*)d_in[5];
  const float* b1 = (const float*)d_in[6];
  const float* g1 = (const float*)d_in[7];
  const float* be1 = (const float*)d_in[8];
  const float* W2 = (const float*)d_in[9];
  const float* b2 = (const float*)d_in[10];
  const float* g2 = (const float*)d_in[11];
  const float* be2 = (const float*)d_in[12];
  const float* bias_vec = (const float*)d_in[13];
  const int* Xi_cat = (const int*)d_in[14];

  constexpr int N = 16384;
  constexpr int DIN = 576;
  constexpr int H = 400;
  constexpr int KP = 416;   // H padded to K-mult-of-32 for gemm2
  constexpr int WPAD = 512; // weight rows padded for unpredicated staging
  constexpr int NXB = 256;  // gemm x-blocks (N/64)

  u16* fm_first = (u16*)d_ws;                        // N*576
  u16* Y1h = fm_first + (size_t)N * DIN;             // N*416
  u16* Y2h = Y1h + (size_t)N * KP;                   // N*400
  u16* W1h = Y2h + (size_t)N * H;                    // 512*576
  u16* W2p = W1h + (size_t)WPAD * DIN;               // 512*416
  float* fptr = (float*)(W2p + (size_t)WPAD * KP);
  float* partial = fptr;                             // N
  float* aS1 = partial + N;                          // 512 (stats, contiguous
  float* aQ1 = aS1 + WPAD;                           //  2048 floats zeroed by
  float* aS2 = aQ1 + WPAD;                           //  embed_prep block 256)
  float* aQ2 = aS2 + WPAD;
  float* b2p = aQ2 + WPAD;                           // 512

  embed_prep<<<256 + 72, 256, 0, stream>>>(Xi_dense, Xv, Wd, bd, tables,
                                           Xi_cat, bias_vec, W1, fm_first,
                                           partial, W1h, aS1);

  gemm_bf16<<<NXB * 4, 256, 0, stream>>>(fm_first, DIN, W1h, DIN, b1, H,
                                         Y1h, KP, KP, aS1, aQ1, DIN);

  prep2<<<128, 256, 0, stream>>>(aS1, aQ1, g1, be1, W2, b2, W2p, b2p);

  gemm_bf16<<<NXB * 4, 256, 0, stream>>>(Y1h, KP, W2p, KP, b2p, H,
                                         Y2h, H, H, aS2, aQ2, KP);

  final_kernel<<<N / 16, 256, 0, stream>>>(Y2h, aS2, aQ2, g2, be2, partial,
                                           (float*)d_out);
}

// Round 10
// 65.271 us; speedup vs baseline: 9.7476x; 1.0693x over previous
//
#include <hip/hip_runtime.h>

#define BN_EPS 1e-5f

typedef unsigned short u16;
typedef __attribute__((ext_vector_type(8))) short bf16x8;
typedef __attribute__((ext_vector_type(4))) float f32x4;

__device__ __forceinline__ u16 f2bf(float x) {
  union { float f; unsigned int u; } v; v.f = x;
  unsigned int r = v.u + 0x7fffu + ((v.u >> 16) & 1u);
  return (u16)(r >> 16);
}
__device__ __forceinline__ float bf2f(u16 h) {
  union { unsigned int u; float f; } v; v.u = ((unsigned int)h) << 16;
  return v.f;
}

__device__ __forceinline__ float wave_reduce_sum(float v) {
#pragma unroll
  for (int off = 1; off < 64; off <<= 1) v += __shfl_xor(v, off, 64);
  return v;
}

// async global->LDS, 16B per lane. LDS dest = wave-uniform base + lane*16.
__device__ __forceinline__ void gload_lds16(const void* g, void* l) {
  __builtin_amdgcn_global_load_lds(
      (const __attribute__((address_space(1))) void*)g,
      (__attribute__((address_space(3))) void*)l, 16, 0, 0);
}

// ---------------------------------------------------------------------------
// embed_prep: blocks [0,512): 32 rows each -> fm_first (bf16) + partial[n].
//   Thread (r=t>>3, q=t&7): 9 bf16x8 chunks, fields f = (q>>1)+4j,
//   e-half (q&1)*8. FM reductions via xor 1/2/4 in the 8-lane row group.
// blocks [512,584): W1 -> W1h bf16 padded to 512 rows; block 512 also zeroes
//   the 4x512 atomic stat accumulators (aS1,aQ1,aS2,aQ2 contiguous).
// NOTE: b1 is NOT applied — train-mode BN is shift-invariant (mean absorbs
// per-column constants), so biases cancel exactly (see prep2/final).
// ---------------------------------------------------------------------------
__global__ __launch_bounds__(256) void embed_prep(
    const float* __restrict__ Xi_dense, const float* __restrict__ Xv,
    const float* __restrict__ Wd, const float* __restrict__ bd,
    const float* __restrict__ tables, const int* __restrict__ Xi_cat,
    const float* __restrict__ bias_vec, const float* __restrict__ W1,
    u16* __restrict__ fm_first, float* __restrict__ partial,
    u16* __restrict__ W1h, float* __restrict__ statz) {
  const int t = threadIdx.x;
  if (blockIdx.x >= 512) {  // W1 conversion region (+ stat zeroing)
    const int bb = blockIdx.x - 512;
    if (bb == 0) {
#pragma unroll
      for (int i = 0; i < 8; ++i) statz[i * 256 + t] = 0.f;  // 2048 floats
    }
    const int base = bb * 4096;
#pragma unroll
    for (int e = 0; e < 16; ++e) {
      const int idx = base + e * 256 + t;
      const int r = idx / 576;
      const int j = idx - r * 576;
      W1h[idx] = (r < 400) ? f2bf(W1[r * 576 + j]) : (u16)0;
    }
    return;
  }

  __shared__ float Xvs[32 * 37];
  __shared__ float Xds[32 * 27];
  __shared__ int Cis[32 * 11];
  __shared__ float Wds[416], Bds[416];
  const int n0 = blockIdx.x * 32;

  for (int i = t; i < 1152; i += 256) {
    const int r = i / 36;
    Xvs[r * 37 + (i - r * 36)] = Xv[n0 * 36 + i];
  }
  for (int i = t; i < 832; i += 256) {
    const int r = i / 26;
    Xds[r * 27 + (i - r * 26)] = Xi_dense[n0 * 26 + i];
  }
  for (int i = t; i < 320; i += 256) {
    const int r = i / 10;
    Cis[r * 11 + (i - r * 10)] = Xi_cat[n0 * 10 + i];
  }
  for (int i = t; i < 416; i += 256) {
    Wds[i] = Wd[i];
    Bds[i] = bd[i];
  }
  __syncthreads();

  const int r = t >> 3, q = t & 7;
  const int n = n0 + r;
  const int fbase = q >> 1, eh = (q & 1) * 8;
  float s8[8] = {}, q8[8] = {};
  float sum_all = 0.f;
  u16* frow = fm_first + (size_t)n * 576;

#pragma unroll
  for (int j = 0; j < 9; ++j) {
    const int f = fbase + 4 * j;
    const float xvv = Xvs[r * 37 + f];
    float val[8];
    if (f < 26) {  // dense field: x*W + b, then scale by xv
      const float xd = Xds[r * 27 + f];
      const float4 w0 = *(const float4*)&Wds[f * 16 + eh];
      const float4 w1 = *(const float4*)&Wds[f * 16 + eh + 4];
      const float4 b0 = *(const float4*)&Bds[f * 16 + eh];
      const float4 b1v = *(const float4*)&Bds[f * 16 + eh + 4];
      val[0] = fmaf(xd, w0.x, b0.x) * xvv;
      val[1] = fmaf(xd, w0.y, b0.y) * xvv;
      val[2] = fmaf(xd, w0.z, b0.z) * xvv;
      val[3] = fmaf(xd, w0.w, b0.w) * xvv;
      val[4] = fmaf(xd, w1.x, b1v.x) * xvv;
      val[5] = fmaf(xd, w1.y, b1v.y) * xvv;
      val[6] = fmaf(xd, w1.z, b1v.z) * xvv;
      val[7] = fmaf(xd, w1.w, b1v.w) * xvv;
    } else {  // categorical gather
      const int fc = f - 26;
      const int row = Cis[r * 11 + fc];
      const float* tp =
          tables + ((size_t)fc * 200000 + (size_t)row) * 16 + eh;
      const float4 v0 = *(const float4*)tp;
      const float4 v1 = *(const float4*)(tp + 4);
      val[0] = v0.x * xvv;
      val[1] = v0.y * xvv;
      val[2] = v0.z * xvv;
      val[3] = v0.w * xvv;
      val[4] = v1.x * xvv;
      val[5] = v1.y * xvv;
      val[6] = v1.z * xvv;
      val[7] = v1.w * xvv;
    }
    bf16x8 o;
#pragma unroll
    for (int jj = 0; jj < 8; ++jj) {
      s8[jj] += val[jj];
      q8[jj] += val[jj] * val[jj];
      sum_all += val[jj];
      o[jj] = (short)f2bf(val[jj]);
    }
    *(bf16x8*)&frow[f * 16 + eh] = o;
  }

  // combine fields across the 4 fbase classes (xor 2,4), per e-column
  float fm2h = 0.f;
#pragma unroll
  for (int jj = 0; jj < 8; ++jj) {
    float se = s8[jj] + __shfl_xor(s8[jj], 2, 64);
    se += __shfl_xor(se, 4, 64);
    float qe = q8[jj] + __shfl_xor(q8[jj], 2, 64);
    qe += __shfl_xor(qe, 4, 64);
    fm2h += se * se - qe;
  }
  const float fm2 = 0.5f * (fm2h + __shfl_xor(fm2h, 1, 64));  // both e-halves
  float srow = sum_all + __shfl_xor(sum_all, 1, 64);
  srow += __shfl_xor(srow, 2, 64);
  srow += __shfl_xor(srow, 4, 64);
  if (q == 0) partial[n] = srow + fm2 + bias_vec[n];
}

// ---------------------------------------------------------------------------
// bf16 MFMA GEMM body (r5-best config, bias-free). BM=64 BN=128 BK=32,
// 256 thr = 4 waves (2x2), 2xNFR 16x16x32 frags/wave. NFR=2: tail tile.
// Stats: per-block column S/Q atomically accumulated into aS/aQ[col].
// ---------------------------------------------------------------------------
template <int NFR>
__device__ __forceinline__ void gemm_body(
    const u16* __restrict__ A, int lda, const u16* __restrict__ W, int ldw,
    u16* __restrict__ Y, int ldc, int Ncap, float* __restrict__ aS,
    float* __restrict__ aQ, int K, int bx, int by, u16* As, u16* Bs,
    float (&rS)[2][4][2][16], float (&rQ)[2][4][2][16]) {
  const int t = threadIdx.x;
  const int bm = bx * 64;
  const int bn = by * 128;
  const int wid = t >> 6, lane = t & 63;
  const int wr = wid >> 1, wc = wid & 1;
  const int lr = lane & 15, lk = (lane >> 4) * 8;
  const int sr = lane >> 2;       // staging row within 16-row chunk
  const int sk = (lane & 3) * 8;  // staging k offset (elements)
  const bool active = (NFR == 4) || (wc == 0);

  f32x4 acc[2][NFR] = {};

  for (int kt = 0; kt < K; kt += 32) {
    gload_lds16(&A[(size_t)(bm + wid * 16 + sr) * lda + kt + sk],
                &As[wid * 512]);
#pragma unroll
    for (int i = 0; i < 2; ++i) {
      const int c = wid * 2 + i;
      if (NFR == 4 || c < 2)
        gload_lds16(&W[(size_t)(bn + c * 16 + sr) * ldw + kt + sk],
                    &Bs[c * 512]);
    }
    __syncthreads();

    if (active) {
      bf16x8 af[2], bfv[NFR];
#pragma unroll
      for (int mf = 0; mf < 2; ++mf)
        af[mf] = *(const bf16x8*)&As[(wr * 32 + mf * 16 + lr) * 32 + lk];
#pragma unroll
      for (int nf = 0; nf < NFR; ++nf)
        bfv[nf] = *(const bf16x8*)&Bs[(wc * 64 + nf * 16 + lr) * 32 + lk];
#pragma unroll
      for (int mf = 0; mf < 2; ++mf)
#pragma unroll
        for (int nf = 0; nf < NFR; ++nf)
          acc[mf][nf] = __builtin_amdgcn_mfma_f32_16x16x32_bf16(
              af[mf], bfv[nf], acc[mf][nf], 0, 0, 0);
    }
    __syncthreads();
  }

  // epilogue: bf16 store, per-block column stats
  const int l4 = (lane >> 4) * 4;
  if (active) {
#pragma unroll
    for (int nf = 0; nf < NFR; ++nf) {
      const int col = bn + wc * 64 + nf * 16 + lr;
      float s = 0.f, q = 0.f;
#pragma unroll
      for (int mf = 0; mf < 2; ++mf) {
#pragma unroll
        for (int r = 0; r < 4; ++r) {
          const int row = bm + wr * 32 + mf * 16 + l4 + r;
          const float v = acc[mf][nf][r];
          s += v;
          q += v * v;
          if (col < Ncap) Y[(size_t)row * ldc + col] = f2bf(v);
        }
      }
      s += __shfl_xor(s, 16, 64);
      s += __shfl_xor(s, 32, 64);
      q += __shfl_xor(q, 16, 64);
      q += __shfl_xor(q, 32, 64);
      if (lane < 16) {
        rS[wc][nf][wr][lr] = s;
        rQ[wc][nf][wr][lr] = q;
      }
    }
  }
  __syncthreads();
  if (t < (NFR == 4 ? 128 : 32)) {  // t == wc*64 + nf*16 + c
    const int wcc = t >> 6, nff = (t >> 4) & 3, c = t & 15;
    atomicAdd(&aS[bn + t], rS[wcc][nff][0][c] + rS[wcc][nff][1][c]);
    atomicAdd(&aQ[bn + t], rQ[wcc][nff][0][c] + rQ[wcc][nff][1][c]);
  }
}

// 1-D grid, y-inner ordering + XCD-chunked swizzle (grid %8 == 0).
__global__ __launch_bounds__(256) void gemm_bf16(
    const u16* __restrict__ A, int lda,
    const u16* __restrict__ W, int ldw,
    u16* __restrict__ Y, int ldc, int Ncap,
    float* __restrict__ aS, float* __restrict__ aQ, int K) {
  __shared__ u16 As[64 * 32];
  __shared__ u16 Bs[128 * 32];
  __shared__ float rS[2][4][2][16];
  __shared__ float rQ[2][4][2][16];
  const int bid = blockIdx.x;
  const int l = (bid & 7) * (gridDim.x >> 3) + (bid >> 3);
  const int bx = l >> 2, by = l & 3;
  if (by < 3)
    gemm_body<4>(A, lda, W, ldw, Y, ldc, Ncap, aS, aQ, K, bx, by, As, Bs,
                 rS, rQ);
  else
    gemm_body<2>(A, lda, W, ldw, Y, ldc, Ncap, aS, aQ, K, bx, by, As, Bs,
                 rS, rQ);
}

// ---------------------------------------------------------------------------
// prep2: W2p[i][j] = bf16(W2[i][j] * a1[j]), a1[j]=g1[j]*rsqrt(var1+eps)
// computed inline from atomic stats. (All bias/shift terms cancel through
// train-mode BN — no dot product needed.)  512x416 output, zeros beyond
// row<400/col<400. One ushort4 chunk per thread; grid 208 x 256.
// ---------------------------------------------------------------------------
__global__ __launch_bounds__(256) void prep2(
    const float* __restrict__ aS1, const float* __restrict__ aQ1,
    const float* __restrict__ g1, const float* __restrict__ W2,
    u16* __restrict__ W2p) {
  const int c = blockIdx.x * 256 + threadIdx.x;  // 512*104 chunks
  const int row = c / 104;
  const int jc = (c - row * 104) * 4;
  ushort4 o = {0, 0, 0, 0};
  if (row < 400 && jc < 400) {
    const float4 S = *(const float4*)&aS1[jc];
    const float4 Q = *(const float4*)&aQ1[jc];
    const float4 G = *(const float4*)&g1[jc];
    const float4 w = *(const float4*)&W2[(size_t)row * 400 + jc];
    const float inv = 1.f / 16384.f;
    float mu, var, a;
    mu = S.x * inv; var = Q.x * inv - mu * mu;
    a = G.x * rsqrtf(var + BN_EPS); o.x = f2bf(w.x * a);
    mu = S.y * inv; var = Q.y * inv - mu * mu;
    a = G.y * rsqrtf(var + BN_EPS); o.y = f2bf(w.y * a);
    mu = S.z * inv; var = Q.z * inv - mu * mu;
    a = G.z * rsqrtf(var + BN_EPS); o.z = f2bf(w.z * a);
    mu = S.w * inv; var = Q.w * inv - mu * mu;
    a = G.w * rsqrtf(var + BN_EPS); o.w = f2bf(w.w * a);
  }
  *(ushort4*)&W2p[(size_t)row * 416 + jc] = o;
}

// ---------------------------------------------------------------------------
// final: BN2 affine inline per lane (8 cols) + out[n] = partial[n] +
// sum_i (a2[i]*(H[n,i]-mu[i]) + be2[i]).  1024 blocks x 4 waves x 4 rows.
// ---------------------------------------------------------------------------
__device__ __forceinline__ void bn_affine4(const float* aS, const float* aQ,
                                           const float* g, const float* be,
                                           int j, float4& aa, float4& cc) {
  const float4 S = *(const float4*)&aS[j];
  const float4 Q = *(const float4*)&aQ[j];
  const float4 G = *(const float4*)&g[j];
  const float4 E = *(const float4*)&be[j];
  const float inv = 1.f / 16384.f;
  float mu, var;
  mu = S.x * inv; var = Q.x * inv - mu * mu;
  aa.x = G.x * rsqrtf(var + BN_EPS); cc.x = E.x - mu * aa.x;
  mu = S.y * inv; var = Q.y * inv - mu * mu;
  aa.y = G.y * rsqrtf(var + BN_EPS); cc.y = E.y - mu * aa.y;
  mu = S.z * inv; var = Q.z * inv - mu * mu;
  aa.z = G.z * rsqrtf(var + BN_EPS); cc.z = E.z - mu * aa.z;
  mu = S.w * inv; var = Q.w * inv - mu * mu;
  aa.w = G.w * rsqrtf(var + BN_EPS); cc.w = E.w - mu * aa.w;
}

__global__ __launch_bounds__(256) void final_kernel(
    const u16* __restrict__ Y2, const float* __restrict__ aS2,
    const float* __restrict__ aQ2, const float* __restrict__ g2,
    const float* __restrict__ be2, const float* __restrict__ partial,
    float* __restrict__ out) {
  const int t = threadIdx.x;
  const int lane = t & 63;
  const int wid = t >> 6;
  const int j0 = lane * 8;
  float ar[8], cr[8];
  if (j0 < 400) {
    float4 aa0, cc0, aa1, cc1;
    bn_affine4(aS2, aQ2, g2, be2, j0, aa0, cc0);
    bn_affine4(aS2, aQ2, g2, be2, j0 + 4, aa1, cc1);
    ar[0] = aa0.x; ar[1] = aa0.y; ar[2] = aa0.z; ar[3] = aa0.w;
    ar[4] = aa1.x; ar[5] = aa1.y; ar[6] = aa1.z; ar[7] = aa1.w;
    cr[0] = cc0.x; cr[1] = cc0.y; cr[2] = cc0.z; cr[3] = cc0.w;
    cr[4] = cc1.x; cr[5] = cc1.y; cr[6] = cc1.z; cr[7] = cc1.w;
  } else {
#pragma unroll
    for (int k = 0; k < 8; ++k) { ar[k] = 0.f; cr[k] = 0.f; }
  }
#pragma unroll
  for (int r = 0; r < 4; ++r) {
    const int n = blockIdx.x * 16 + wid * 4 + r;
    float acc = 0.f;
    if (j0 < 400) {
      const bf16x8 y = *(const bf16x8*)&Y2[(size_t)n * 400 + j0];
#pragma unroll
      for (int k = 0; k < 8; ++k)
        acc += fmaf(ar[k], bf2f((u16)y[k]), cr[k]);
    }
    acc = wave_reduce_sum(acc);
    if (lane == 0) out[n] = partial[n] + acc;
  }
}

extern "C" void kernel_launch(void* const* d_in, const int* in_sizes, int n_in,
                              void* d_out, int out_size, void* d_ws,
                              size_t ws_size, hipStream_t stream) {
  const float* Xi_dense = (const float*)d_in[0];
  const float* Xv = (const float*)d_in[1];
  const float* Wd = (const float*)d_in[2];
  const float* bd = (const float*)d_in[3];
  const float* tables = (const float*)d_in[4];
  const float* W1 = (const float*)d_in[5];
  const float* g1 = (const float*)d_in[7];
  const float* W2 = (const float*)d_in[9];
  const float* g2 = (const float*)d_in[11];
  const float* be2 = (const float*)d_in[12];
  const float* bias_vec = (const float*)d_in[13];
  const int* Xi_cat = (const int*)d_in[14];

  constexpr int N = 16384;
  constexpr int DIN = 576;
  constexpr int H = 400;
  constexpr int KP = 416;   // H padded to K-mult-of-32 for gemm2
  constexpr int WPAD = 512; // weight rows padded for unpredicated staging
  constexpr int NXB = 256;  // gemm x-blocks (N/64)

  u16* fm_first = (u16*)d_ws;                        // N*576
  u16* Y1h = fm_first + (size_t)N * DIN;             // N*416
  u16* Y2h = Y1h + (size_t)N * KP;                   // N*400
  u16* W1h = Y2h + (size_t)N * H;                    // 512*576
  u16* W2p = W1h + (size_t)WPAD * DIN;               // 512*416
  float* fptr = (float*)(W2p + (size_t)WPAD * KP);
  float* partial = fptr;                             // N
  float* aS1 = partial + N;                          // 512 (stats; 2048
  float* aQ1 = aS1 + WPAD;                           //  floats zeroed by
  float* aS2 = aQ1 + WPAD;                           //  embed block 512)
  float* aQ2 = aS2 + WPAD;

  embed_prep<<<512 + 72, 256, 0, stream>>>(Xi_dense, Xv, Wd, bd, tables,
                                           Xi_cat, bias_vec, W1, fm_first,
                                           partial, W1h, aS1);

  gemm_bf16<<<NXB * 4, 256, 0, stream>>>(fm_first, DIN, W1h, DIN,
                                         Y1h, KP, KP, aS1, aQ1, DIN);

  prep2<<<208, 256, 0, stream>>>(aS1, aQ1, g1, W2, W2p);

  gemm_bf16<<<NXB * 4, 256, 0, stream>>>(Y1h, KP, W2p, KP,
                                         Y2h, H, H, aS2, aQ2, KP);

  final_kernel<<<N / 16, 256, 0, stream>>>(Y2h, aS2, aQ2, g2, be2, partial,
                                           (float*)d_out);
}